// Round 10
// baseline (439.484 us; speedup 1.0000x reference)
//
#include <hip/hip_runtime.h>

// ---------------------------------------------------------------------------
// 2-layer GCN, symmetric norm + self loops — rank-2 scalarized, LDS-atomic
// segment sums over a dst-bucket partition, SPLIT sub-blocks per bucket,
// last-arrival fusion for all glue stages.
//
// feat is [n,1] and b1 == 0 (device-checked)  =>
//   px_v = dinv_v * (g_v + sum g_src),  g = dinv*feat
//   qs_v = dinv_v * px_v   (signed; q± = relu(±qs), only one nonzero)
//   out[v,k] = relu( dinv_v (S+_v u+[k] + S-_v u-[k]) + b2[k] ),
//   S±_v = relu(±qs_v) + sum relu(±qs_src),  u± = max(±W1,0) @ W2 (2x64)
//
// R4: global f32 atomics ~32B HBM writeback each -> never per-edge.
// R5: partition scatter needs >=128B per-bucket runs (NCHUNK=256, SBSZ=256).
// R6: agg kernels need high occupancy for gather latency.
// R7: per-CU LDS atomic pipe saturates (~4cy/lane-op) -> 1 atomic/edge max.
// R8/R9: deterministic 2D-histogram partition (1 atomic/edge, no reservation).
// R10: last-arrival fusion (syncthreads drains stores to L2 on CDNA; one
//      counter atomic per block; last block does the dependent node-parallel
//      stage) removes 4 launches incl. the 25.6MB k_out epilogue; paired-edge
//      int4/int2 loads in hist/partition halve their load-issue.
// ---------------------------------------------------------------------------

#define TPB 256
#define TPBW 1024     // wide blocks: hist + partition
#define NSBMAX 1024   // max buckets (LDS arrays)
#define SBSZ 256      // nodes per bucket (= 1 << LBITS)
#define LBITS 8
#define SPLIT 4       // sub-blocks per bucket in agg kernels
#define NCHUNK 256    // edge chunks (= partition/hist grid)

// Fused init: edge-layout detect (int64 low/high pairs vs int32; ids < 2^31
// so int64 high words are 0 — sample odd 32-bit positions) + u± = max(±W1,0)@W2
// + bzero = all(b1==0) + zero arrival counters. One block.
__global__ void k_init(const int* __restrict__ e32, int E, int* __restrict__ flag,
                       const float* __restrict__ W1, const float* __restrict__ b1,
                       const float* __restrict__ W2, float* __restrict__ upm,
                       int* __restrict__ bzero, int* __restrict__ ctrs, int nctr) {
    __shared__ int ok;
    __shared__ float sw[32], sb[32];
    int t = threadIdx.x;
    if (t == 0) ok = 1;
    if (t < 32) { sw[t] = W1[t]; sb[t] = b1[t]; }
    for (int i = t; i < nctr; i += TPB) ctrs[i] = 0;
    __syncthreads();
    int stride = E / 2048; if (stride < 1) stride = 1;
    bool bad = false;
#pragma unroll
    for (int i = 0; i < 8; ++i) {
        long k = (long)(t * 8 + i) * stride + 1;
        if (k < E && e32[2 * k + 1] != 0) bad = true;
    }
    if (bad) atomicAnd(&ok, 0);
    if (t < 64) {
        float up = 0.f, um = 0.f;
#pragma unroll
        for (int c = 0; c < 32; ++c) {
            float w = sw[c];
            float w2 = W2[c * 64 + t];
            up = fmaf(fmaxf(w, 0.f), w2, up);
            um = fmaf(fmaxf(-w, 0.f), w2, um);
        }
        upm[t] = up;
        upm[64 + t] = um;
    }
    __syncthreads();
    if (t == 0) {
        *flag = ok;   // 1 => int64 (shift 1), 0 => int32
        int z = 1;
        for (int c = 0; c < 32; ++c) if (sb[c] != 0.f) z = 0;
        *bzero = z;
    }
}

// per-chunk bucket histogram; stores the FULL row H[c][b]. Paired-edge loads.
__global__ void k_hist2(const int* __restrict__ e32, const int* __restrict__ flag,
                        int E, int NSB, int chunk, int* __restrict__ H) {
    __shared__ int sh[NSBMAX];
    int c = blockIdx.x;
    int c0 = c * chunk;
    int c1 = c0 + chunk; if (c1 > E) c1 = E;
    for (int i = threadIdx.x; i < NSB; i += TPBW) sh[i] = 0;
    __syncthreads();
    int f = *flag;
    if (((E | c0) & 1) == 0) {          // aligned paired path
        if (f) {
            const int4* d4 = (const int4*)e32;
            for (int e = c0 + threadIdx.x * 2; e < c1; e += TPBW * 2) {
                int4 dd = d4[(E + e) >> 1];          // dsts of e, e+1 at .x, .z
                atomicAdd(&sh[dd.x >> LBITS], 1);
                if (e + 1 < c1) atomicAdd(&sh[dd.z >> LBITS], 1);
            }
        } else {
            const int2* d2 = (const int2*)e32;
            for (int e = c0 + threadIdx.x * 2; e < c1; e += TPBW * 2) {
                int2 dd = d2[(E + e) >> 1];          // dsts of e, e+1
                atomicAdd(&sh[dd.x >> LBITS], 1);
                if (e + 1 < c1) atomicAdd(&sh[dd.y >> LBITS], 1);
            }
        }
    } else {
        for (int e = c0 + threadIdx.x; e < c1; e += TPBW) {
            int d = e32[((long)E + e) << f];
            atomicAdd(&sh[d >> LBITS], 1);
        }
    }
    __syncthreads();
    for (int i = threadIdx.x; i < NSB; i += TPBW) H[(size_t)c * NSB + i] = sh[i];
}

// per bucket: exclusive scan of H column over chunks -> P2, colsum;
// LAST-ARRIVAL block also scans colsum -> base (fused k_scan).
__global__ void k_colscan(const int* __restrict__ H, int NSB, int E,
                          int* __restrict__ P2, int* __restrict__ colsum,
                          int* __restrict__ base, int* __restrict__ ctr) {
    __shared__ int s[NCHUNK];
    __shared__ int s2a[TPB];
    __shared__ int lastf;
    int b = blockIdx.x, t = threadIdx.x;
    int v = H[(size_t)t * NSB + b];
    s[t] = v;
    __syncthreads();
    for (int off = 1; off < NCHUNK; off <<= 1) {
        int x = s[t];
        int u = (t >= off) ? s[t - off] : 0;
        __syncthreads();
        s[t] = x + u;
        __syncthreads();
    }
    P2[(size_t)t * NSB + b] = s[t] - v;
    if (t == NCHUNK - 1) colsum[b] = s[t];
    __syncthreads();                          // drains stores (vmcnt) pre-barrier
    if (t == 0) { __threadfence(); lastf = (atomicAdd(ctr, 1) == gridDim.x - 1); }
    __syncthreads();
    if (!lastf) return;
    __threadfence();
    int K = (NSB + TPB - 1) / TPB;
    int i0 = t * K;
    int tot = 0;
    for (int k = 0; k < K; ++k) { int i = i0 + k; if (i < NSB) tot += colsum[i]; }
    s2a[t] = tot;
    __syncthreads();
    for (int off = 1; off < TPB; off <<= 1) {
        int x = s2a[t];
        int u = (t >= off) ? s2a[t - off] : 0;
        __syncthreads();
        s2a[t] = x + u;
        __syncthreads();
    }
    int run = s2a[t] - tot;   // exclusive
    for (int k = 0; k < K; ++k) {
        int i = i0 + k;
        if (i < NSB) { base[i] = run; run += colsum[i]; }
    }
    if (t == 0) base[NSB] = E;
}

// partition bucket-major with deterministic offsets (base[b]+P2[c][b]);
// ONE LDS atomic per edge; paired-edge loads; packed (ldst<<24)|src.
__global__ void k_part2(const int* __restrict__ e32, const int* __restrict__ flag,
                        int E, int NSB, const int* __restrict__ base,
                        const int* __restrict__ P2, unsigned int* __restrict__ P,
                        int chunk) {
    __shared__ int sh[NSBMAX];
    int c = blockIdx.x;
    int c0 = c * chunk;
    int c1 = c0 + chunk; if (c1 > E) c1 = E;
    for (int i = threadIdx.x; i < NSB; i += TPBW)
        sh[i] = base[i] + P2[(size_t)c * NSB + i];
    __syncthreads();
    int f = *flag;
    int sshift = 32 - LBITS;
    if (((E | c0) & 1) == 0) {
        if (f) {
            const int4* s4 = (const int4*)e32;
            for (int e = c0 + threadIdx.x * 2; e < c1; e += TPBW * 2) {
                int4 ss = s4[e >> 1];                // srcs of e, e+1 at .x, .z
                int4 dd = s4[(E + e) >> 1];          // dsts of e, e+1 at .x, .z
                int b0 = dd.x >> LBITS;
                int pos0 = atomicAdd(&sh[b0], 1);
                P[pos0] = (unsigned)ss.x | ((unsigned)(dd.x & (SBSZ - 1)) << sshift);
                if (e + 1 < c1) {
                    int b1i = dd.z >> LBITS;
                    int pos1 = atomicAdd(&sh[b1i], 1);
                    P[pos1] = (unsigned)ss.z | ((unsigned)(dd.z & (SBSZ - 1)) << sshift);
                }
            }
        } else {
            const int2* s2 = (const int2*)e32;
            for (int e = c0 + threadIdx.x * 2; e < c1; e += TPBW * 2) {
                int2 ss = s2[e >> 1];
                int2 dd = s2[(E + e) >> 1];
                int b0 = dd.x >> LBITS;
                int pos0 = atomicAdd(&sh[b0], 1);
                P[pos0] = (unsigned)ss.x | ((unsigned)(dd.x & (SBSZ - 1)) << sshift);
                if (e + 1 < c1) {
                    int b1i = dd.y >> LBITS;
                    int pos1 = atomicAdd(&sh[b1i], 1);
                    P[pos1] = (unsigned)ss.y | ((unsigned)(dd.y & (SBSZ - 1)) << sshift);
                }
            }
        }
    } else {
        for (int e = c0 + threadIdx.x; e < c1; e += TPBW) {
            long ee = (long)e << f;
            int s = e32[ee];
            int d = e32[(((long)E) << f) + ee];
            int b = d >> LBITS;
            int pos = atomicAdd(&sh[b], 1);
            P[pos] = (unsigned)s | ((unsigned)(d & (SBSZ - 1)) << sshift);
        }
    }
}

// per (bucket, quarter): LDS degree histogram -> partial store; LAST-ARRIVAL
// block (per bucket) computes dinv,g for the bucket's nodes (fused k_prep1).
__global__ void k_degSP(const unsigned int* __restrict__ P, const int* __restrict__ base,
                        int n, const float* __restrict__ feat, int* __restrict__ cntP,
                        float* __restrict__ dinv, float* __restrict__ g,
                        int* __restrict__ ctrE) {
    __shared__ int cnt[SBSZ];
    __shared__ int lastf;
    int bb = blockIdx.x >> 2, pp = blockIdx.x & (SPLIT - 1);
    int t = threadIdx.x;
    cnt[t] = 0;
    __syncthreads();
    int p0 = base[bb], len = base[bb + 1] - p0;
    int s0 = p0 + (int)((long)len * pp / SPLIT);
    int s1 = p0 + (int)((long)len * (pp + 1) / SPLIT);
    int sshift = 32 - LBITS;
    for (int p = s0 + t; p < s1; p += TPB)
        atomicAdd(&cnt[P[p] >> sshift], 1);
    __syncthreads();
    int v = (bb << LBITS) + t;
    if (v < n) cntP[pp * n + v] = cnt[t];
    __syncthreads();
    if (t == 0) { __threadfence(); lastf = (atomicAdd(&ctrE[bb], 1) == SPLIT - 1); }
    __syncthreads();
    if (!lastf) return;
    __threadfence();
    if (v < n) {
        int c = 0;
#pragma unroll
        for (int q = 0; q < SPLIT; ++q) c += cntP[q * n + v];
        float di = rsqrtf((float)(c + 1));
        dinv[v] = di;
        g[v] = di * feat[v];
    }
}

// per (bucket, quarter): partial A sums (1 LDS f32 atomic/edge); LAST-ARRIVAL
// computes px -> qs (and pd/Yagg-zero for the general path) (fused k_prep2).
__global__ void k_aggASP(const unsigned int* __restrict__ P, const int* __restrict__ base,
                         int n, const float* __restrict__ g, const float* __restrict__ dinv,
                         const int* __restrict__ bzero, float* __restrict__ AP,
                         float* __restrict__ qs, float2* __restrict__ pd,
                         float* __restrict__ Yagg, int* __restrict__ ctrF) {
    __shared__ float A[SBSZ];
    __shared__ int lastf;
    int bb = blockIdx.x >> 2, pp = blockIdx.x & (SPLIT - 1);
    int t = threadIdx.x;
    A[t] = 0.f;
    __syncthreads();
    int p0 = base[bb], len = base[bb + 1] - p0;
    int s0 = p0 + (int)((long)len * pp / SPLIT);
    int s1 = p0 + (int)((long)len * (pp + 1) / SPLIT);
    int sshift = 32 - LBITS;
    unsigned smask = (1u << sshift) - 1;
    for (int p = s0 + t; p < s1; p += TPB) {
        unsigned e = P[p];
        atomicAdd(&A[e >> sshift], g[e & smask]);
    }
    __syncthreads();
    int v = (bb << LBITS) + t;
    if (v < n) AP[pp * n + v] = A[t];
    __syncthreads();
    if (t == 0) { __threadfence(); lastf = (atomicAdd(&ctrF[bb], 1) == SPLIT - 1); }
    __syncthreads();
    if (!lastf) return;
    __threadfence();
    if (v < n) {
        float Av = g[v];
#pragma unroll
        for (int q = 0; q < SPLIT; ++q) Av += AP[q * n + v];
        float di = dinv[v];
        float px = di * Av;
        qs[v] = di * px;
        if (!*bzero) {
            pd[v] = make_float2(px, di);
            float4* Y = (float4*)(Yagg + (size_t)v * 32);
#pragma unroll
            for (int i = 0; i < 8; ++i) Y[i] = make_float4(0.f, 0.f, 0.f, 0.f);
        }
    }
}

// per (bucket, quarter): S± partials, ONE LDS atomic/edge (sign trick);
// LAST-ARRIVAL block computes the bucket's 256x64 outputs (fused k_out).
__global__ void k_aggTSP(const unsigned int* __restrict__ P, const int* __restrict__ base,
                         int n, const float* __restrict__ qs, const float* __restrict__ dinv,
                         const float* __restrict__ upm, const float* __restrict__ b2,
                         const int* __restrict__ bzero, float2* __restrict__ SP2,
                         float* __restrict__ out, int* __restrict__ ctrG) {
    __shared__ float Sp[SBSZ], Sm[SBSZ];
    __shared__ float su[192];    // u+ | u- | b2
    __shared__ int lastf;
    int bb = blockIdx.x >> 2, pp = blockIdx.x & (SPLIT - 1);
    int t = threadIdx.x;
    Sp[t] = 0.f; Sm[t] = 0.f;
    __syncthreads();
    int p0 = base[bb], len = base[bb + 1] - p0;
    int s0 = p0 + (int)((long)len * pp / SPLIT);
    int s1 = p0 + (int)((long)len * (pp + 1) / SPLIT);
    int sshift = 32 - LBITS;
    unsigned smask = (1u << sshift) - 1;
    for (int p = s0 + t; p < s1; p += TPB) {
        unsigned e = P[p];
        float q = qs[e & smask];
        int l = e >> sshift;
        float* addr = (q >= 0.f) ? &Sp[l] : &Sm[l];
        atomicAdd(addr, fabsf(q));
    }
    __syncthreads();
    int v0 = bb << LBITS;
    int v = v0 + t;
    if (v < n) SP2[pp * n + v] = make_float2(Sp[t], Sm[t]);
    __syncthreads();
    if (t == 0) { __threadfence(); lastf = (atomicAdd(&ctrG[bb], 1) == SPLIT - 1); }
    __syncthreads();
    if (!lastf || !*bzero) return;
    __threadfence();
    // stage per-node dinv-premultiplied totals in LDS (reuse Sp/Sm)
    if (t < 192) su[t] = (t < 192) ? ((t < 128) ? upm[t] : b2[t - 128]) : 0.f;
    float Fp = 0.f, Fm = 0.f;
    if (v < n) {
        float qv = qs[v];
        float sp = fmaxf(qv, 0.f), sm = fmaxf(-qv, 0.f);
#pragma unroll
        for (int q = 0; q < SPLIT; ++q) { float2 s2v = SP2[q * n + v]; sp += s2v.x; sm += s2v.y; }
        float di = dinv[v];
        Fp = di * sp; Fm = di * sm;
    }
    __syncthreads();
    Sp[t] = Fp; Sm[t] = Fm;
    __syncthreads();
    int nv = n - v0; if (nv > SBSZ) nv = SBSZ; if (nv < 0) nv = 0;
    for (int o = t; o < nv * 64; o += TPB) {
        int vl = o >> 6, k = o & 63;
        float r = fmaf(Sp[vl], su[k], fmaf(Sm[vl], su[64 + k], su[128 + k]));
        out[(size_t)(v0 + vl) * 64 + k] = fmaxf(r, 0.f);
    }
}

// ---- general-b1 fallback (flag-gated; never taken in this bench) ----
__global__ void k_aggY(const int* __restrict__ e32, const int* __restrict__ flag,
                       int E, const int* __restrict__ bzero,
                       const float2* __restrict__ pd,
                       const float* __restrict__ W1, const float* __restrict__ b1,
                       float* __restrict__ Yagg) {
    if (*bzero) return;
    __shared__ float sw[32], sb[32];
    if (threadIdx.x < 32) { sw[threadIdx.x] = W1[threadIdx.x]; sb[threadIdx.x] = b1[threadIdx.x]; }
    __syncthreads();
    int sh = *flag;
    long stride = (long)gridDim.x * TPB;
    for (long e = (long)blockIdx.x * TPB + threadIdx.x; e < E; e += stride) {
        int s = e32[e << sh];
        int d = e32[((long)E + e) << sh];
        float2 p = pd[s];
#pragma unroll
        for (int c = 0; c < 32; ++c) {
            float y = p.y * fmaxf(fmaf(sw[c], p.x, sb[c] * p.y), 0.f);
            atomicAdd(&Yagg[(size_t)d * 32 + c], y);
        }
    }
}

__global__ void k_final_gen(const float2* __restrict__ pd, const float* __restrict__ Yagg,
                            const float* __restrict__ W1, const float* __restrict__ b1,
                            const float* __restrict__ W2, const float* __restrict__ b2,
                            const int* __restrict__ bzero, int n, float* __restrict__ out) {
    if (*bzero) return;
    __shared__ float sW[32 * 64];
    __shared__ float sb2[64];
    __shared__ float sagg[8][33];
    int t = threadIdx.x;
    for (int i = t; i < 32 * 64; i += TPB) sW[i] = W2[i];
    if (t < 64) sb2[t] = b2[t];
    int vl = t >> 5, c = t & 31;
    int nblk = (n + 7) / 8;
    for (int blk = blockIdx.x; blk < nblk; blk += gridDim.x) {
        int v = blk * 8 + vl;
        float a = 0.f;
        if (v < n) {
            float2 p = pd[v];
            float dv = p.y;
            float yv = fmaxf(fmaf(W1[c], p.x, b1[c] * p.y), 0.f);
            a = dv * (dv * yv + Yagg[(size_t)v * 32 + c]);
        }
        __syncthreads();
        sagg[vl][c] = a;
        __syncthreads();
        if (v < n) {
            float o0 = sb2[c], o1 = sb2[c + 32];
#pragma unroll
            for (int j = 0; j < 32; ++j) {
                float x = sagg[vl][j];
                o0 += x * sW[j * 64 + c];
                o1 += x * sW[j * 64 + 32 + c];
            }
            out[(size_t)v * 64 + c]      = fmaxf(o0, 0.f);
            out[(size_t)v * 64 + 32 + c] = fmaxf(o1, 0.f);
        }
    }
}

static inline size_t align256(size_t x) { return (x + 255) & ~(size_t)255; }

extern "C" void kernel_launch(void* const* d_in, const int* in_sizes, int n_in,
                              void* d_out, int out_size, void* d_ws, size_t ws_size,
                              hipStream_t stream) {
    const float* feat = (const float*)d_in[0];
    const int*   e32  = (const int*)d_in[1];
    const float* W1   = (const float*)d_in[2];
    const float* b1   = (const float*)d_in[3];
    const float* W2   = (const float*)d_in[4];
    const float* b2   = (const float*)d_in[5];
    float* out = (float*)d_out;

    int n = in_sizes[0];         // 100000
    int E = in_sizes[1] / 2;     // 3200000

    int NSB = (n + SBSZ - 1) >> LBITS;                    // 391 @ n=100K
    int nctr = 1 + 3 * NSB;

    char* w = (char*)d_ws;
    size_t off = 0;
    auto alloc = [&](size_t bytes) -> char* { char* p = w + off; off = align256(off + bytes); return p; };
    unsigned int* P = (unsigned int*)alloc((size_t)E * 4);
    int*    H     = (int*)alloc((size_t)NCHUNK * NSB * 4);
    int*    P2    = (int*)alloc((size_t)NCHUNK * NSB * 4);
    int*    colsum= (int*)alloc((size_t)NSB * 4);
    int*    base  = (int*)alloc((size_t)(NSB + 1) * 4);
    int*    cntP  = (int*)alloc((size_t)SPLIT * n * 4);
    float*  AP    = (float*)alloc((size_t)SPLIT * n * 4);
    float2* SP2   = (float2*)alloc((size_t)SPLIT * n * 8);
    float*  dinv  = (float*)alloc((size_t)n * 4);
    float*  g     = (float*)alloc((size_t)n * 4);
    float*  qs    = (float*)alloc((size_t)n * 4);
    float2* pd    = (float2*)alloc((size_t)n * 8);
    float*  upm   = (float*)alloc(128 * 4);
    int*    flag  = (int*)alloc(4);
    int*    bzero = (int*)alloc(4);
    int*    ctrs  = (int*)alloc((size_t)nctr * 4);
    float*  Yagg  = (float*)alloc((size_t)n * 32 * 4);    // general path only

    int* ctrC = ctrs;            // colscan arrival (1)
    int* ctrE = ctrs + 1;        // degSP arrivals (NSB)
    int* ctrF = ctrs + 1 + NSB;  // aggASP arrivals (NSB)
    int* ctrG = ctrs + 1 + 2 * NSB;  // aggTSP arrivals (NSB)

    int chunk = (E + NCHUNK - 1) / NCHUNK;
    if (chunk & 1) chunk++;                  // even chunk => aligned paired loads
    int gS = NSB * SPLIT;

    hipLaunchKernelGGL(k_init,      dim3(1),      dim3(TPB),  0, stream, e32, E, flag, W1, b1, W2, upm, bzero, ctrs, nctr);
    hipLaunchKernelGGL(k_hist2,     dim3(NCHUNK), dim3(TPBW), 0, stream, e32, flag, E, NSB, chunk, H);
    hipLaunchKernelGGL(k_colscan,   dim3(NSB),    dim3(NCHUNK), 0, stream, H, NSB, E, P2, colsum, base, ctrC);
    hipLaunchKernelGGL(k_part2,     dim3(NCHUNK), dim3(TPBW), 0, stream, e32, flag, E, NSB, base, P2, P, chunk);
    hipLaunchKernelGGL(k_degSP,     dim3(gS),     dim3(TPB),  0, stream, P, base, n, feat, cntP, dinv, g, ctrE);
    hipLaunchKernelGGL(k_aggASP,    dim3(gS),     dim3(TPB),  0, stream, P, base, n, g, dinv, bzero, AP, qs, pd, Yagg, ctrF);
    hipLaunchKernelGGL(k_aggTSP,    dim3(gS),     dim3(TPB),  0, stream, P, base, n, qs, dinv, upm, b2, bzero, SP2, out, ctrG);
    hipLaunchKernelGGL(k_aggY,      dim3(512),    dim3(TPB),  0, stream, e32, flag, E, bzero, pd, W1, b1, Yagg);
    hipLaunchKernelGGL(k_final_gen, dim3(1024),   dim3(TPB),  0, stream, pd, Yagg, W1, b1, W2, b2, bzero, n, out);
}

// Round 11
// 120.797 us; speedup vs baseline: 3.6382x; 3.6382x over previous
//
#include <hip/hip_runtime.h>

// ---------------------------------------------------------------------------
// 2-layer GCN, symmetric norm + self loops — rank-2 scalarized, LDS-atomic
// segment sums over a dst-bucket partition, SPLIT sub-blocks per bucket.
//
// feat is [n,1] and b1 == 0 (device-checked)  =>
//   px_v = dinv_v * (g_v + sum g_src),  g = dinv*feat
//   qs_v = dinv_v * px_v   (signed; q± = relu(±qs), only one nonzero)
//   out[v,k] = relu( dinv_v (S+_v u+[k] + S-_v u-[k]) + b2[k] ),
//   S±_v = relu(±qs_v) + sum relu(±qs_src),  u± = max(±W1,0) @ W2 (2x64)
//
// R4: global f32 atomics ~32B HBM writeback each -> never per-edge.
// R5: partition scatter needs >=128B per-bucket runs (NCHUNK=256, SBSZ=256).
// R6: agg kernels need high occupancy to hide gather latency.
// R7: per-CU LDS atomic pipe saturates (~4cy/lane-op) -> 1 atomic/edge max.
// R8/R9: deterministic 2D-histogram partition (1 atomic/edge, no reservation).
// R10 REGRESSION lesson: __threadfence() (device-scope fence) on gfx950 does
//    an L2 writeback/invalidate for cross-XCD visibility; per-block fences
//    (last-arrival fusion) cost ~100µs+. A kernel launch IS the cheap global
//    barrier — keep stages as separate kernels. Kept only the fence-free
//    gains: paired int4/int2 edge loads in hist/partition.
// ---------------------------------------------------------------------------

#define TPB 256
#define TPBW 1024     // wide blocks: hist + partition
#define NSBMAX 1024   // max buckets (LDS arrays)
#define SBSZ 256      // nodes per bucket (= 1 << LBITS)
#define LBITS 8
#define SPLIT 4       // sub-blocks per bucket in agg kernels
#define NCHUNK 256    // edge chunks (= partition/hist grid)

// Fused init: edge-layout detect (int64 low/high pairs vs int32; ids < 2^31
// so int64 high words are 0 — sample odd 32-bit positions) + u± = max(±W1,0)@W2
// + bzero = all(b1==0). One block.
__global__ void k_init(const int* __restrict__ e32, int E, int* __restrict__ flag,
                       const float* __restrict__ W1, const float* __restrict__ b1,
                       const float* __restrict__ W2, float* __restrict__ upm,
                       int* __restrict__ bzero) {
    __shared__ int ok;
    __shared__ float sw[32], sb[32];
    int t = threadIdx.x;
    if (t == 0) ok = 1;
    if (t < 32) { sw[t] = W1[t]; sb[t] = b1[t]; }
    __syncthreads();
    int stride = E / 2048; if (stride < 1) stride = 1;
    bool bad = false;
#pragma unroll
    for (int i = 0; i < 8; ++i) {
        long k = (long)(t * 8 + i) * stride + 1;
        if (k < E && e32[2 * k + 1] != 0) bad = true;
    }
    if (bad) atomicAnd(&ok, 0);
    if (t < 64) {
        float up = 0.f, um = 0.f;
#pragma unroll
        for (int c = 0; c < 32; ++c) {
            float w = sw[c];
            float w2 = W2[c * 64 + t];
            up = fmaf(fmaxf(w, 0.f), w2, up);
            um = fmaf(fmaxf(-w, 0.f), w2, um);
        }
        upm[t] = up;
        upm[64 + t] = um;
    }
    __syncthreads();
    if (t == 0) {
        *flag = ok;   // 1 => int64 (shift 1), 0 => int32
        int z = 1;
        for (int c = 0; c < 32; ++c) if (sb[c] != 0.f) z = 0;
        *bzero = z;
    }
}

// per-chunk bucket histogram; stores the FULL row H[c][b]. Paired-edge loads
// (chunk is even, E even => aligned int4/int2 pairs).
__global__ void k_hist2(const int* __restrict__ e32, const int* __restrict__ flag,
                        int E, int NSB, int chunk, int* __restrict__ H) {
    __shared__ int sh[NSBMAX];
    int c = blockIdx.x;
    int c0 = c * chunk;
    int c1 = c0 + chunk; if (c1 > E) c1 = E;
    for (int i = threadIdx.x; i < NSB; i += TPBW) sh[i] = 0;
    __syncthreads();
    int f = *flag;
    if (((E | c0) & 1) == 0) {
        if (f) {
            const int4* d4 = (const int4*)e32;
            for (int e = c0 + threadIdx.x * 2; e < c1; e += TPBW * 2) {
                int4 dd = d4[(E + e) >> 1];          // dsts of e, e+1 at .x, .z
                atomicAdd(&sh[dd.x >> LBITS], 1);
                if (e + 1 < c1) atomicAdd(&sh[dd.z >> LBITS], 1);
            }
        } else {
            const int2* d2 = (const int2*)e32;
            for (int e = c0 + threadIdx.x * 2; e < c1; e += TPBW * 2) {
                int2 dd = d2[(E + e) >> 1];
                atomicAdd(&sh[dd.x >> LBITS], 1);
                if (e + 1 < c1) atomicAdd(&sh[dd.y >> LBITS], 1);
            }
        }
    } else {
        for (int e = c0 + threadIdx.x; e < c1; e += TPBW) {
            int d = e32[((long)E + e) << f];
            atomicAdd(&sh[d >> LBITS], 1);
        }
    }
    __syncthreads();
    for (int i = threadIdx.x; i < NSB; i += TPBW) H[(size_t)c * NSB + i] = sh[i];
}

// per bucket: exclusive scan of H column over chunks -> P2; total -> colsum
__global__ void k_colscan(const int* __restrict__ H, int NSB,
                          int* __restrict__ P2, int* __restrict__ colsum) {
    __shared__ int s[NCHUNK];
    int b = blockIdx.x, t = threadIdx.x;
    int v = H[(size_t)t * NSB + b];
    s[t] = v;
    __syncthreads();
    for (int off = 1; off < NCHUNK; off <<= 1) {
        int x = s[t];
        int u = (t >= off) ? s[t - off] : 0;
        __syncthreads();
        s[t] = x + u;
        __syncthreads();
    }
    P2[(size_t)t * NSB + b] = s[t] - v;
    if (t == NCHUNK - 1) colsum[b] = s[t];
}

// one-block exclusive scan of NSB bucket totals -> base
__global__ void k_scan(const int* __restrict__ colsum, int NSB, int E,
                       int* __restrict__ base) {
    __shared__ int s[TPB];
    int K = (NSB + TPB - 1) / TPB;
    int t = threadIdx.x;
    int i0 = t * K;
    int tot = 0;
    for (int k = 0; k < K; ++k) { int i = i0 + k; if (i < NSB) tot += colsum[i]; }
    s[t] = tot;
    __syncthreads();
    for (int off = 1; off < TPB; off <<= 1) {
        int v = s[t];
        int u = (t >= off) ? s[t - off] : 0;
        __syncthreads();
        s[t] = v + u;
        __syncthreads();
    }
    int run = s[t] - tot;   // exclusive
    for (int k = 0; k < K; ++k) {
        int i = i0 + k;
        if (i < NSB) { base[i] = run; run += colsum[i]; }
    }
    if (t == 0) base[NSB] = E;
}

// partition bucket-major with deterministic offsets (base[b]+P2[c][b]);
// ONE LDS atomic per edge; paired-edge loads; packed (ldst<<24)|src.
__global__ void k_part2(const int* __restrict__ e32, const int* __restrict__ flag,
                        int E, int NSB, const int* __restrict__ base,
                        const int* __restrict__ P2, unsigned int* __restrict__ P,
                        int chunk) {
    __shared__ int sh[NSBMAX];
    int c = blockIdx.x;
    int c0 = c * chunk;
    int c1 = c0 + chunk; if (c1 > E) c1 = E;
    for (int i = threadIdx.x; i < NSB; i += TPBW)
        sh[i] = base[i] + P2[(size_t)c * NSB + i];
    __syncthreads();
    int f = *flag;
    int sshift = 32 - LBITS;
    if (((E | c0) & 1) == 0) {
        if (f) {
            const int4* s4 = (const int4*)e32;
            for (int e = c0 + threadIdx.x * 2; e < c1; e += TPBW * 2) {
                int4 ss = s4[e >> 1];                // srcs of e, e+1 at .x, .z
                int4 dd = s4[(E + e) >> 1];          // dsts of e, e+1 at .x, .z
                int b0 = dd.x >> LBITS;
                int pos0 = atomicAdd(&sh[b0], 1);
                P[pos0] = (unsigned)ss.x | ((unsigned)(dd.x & (SBSZ - 1)) << sshift);
                if (e + 1 < c1) {
                    int b1i = dd.z >> LBITS;
                    int pos1 = atomicAdd(&sh[b1i], 1);
                    P[pos1] = (unsigned)ss.z | ((unsigned)(dd.z & (SBSZ - 1)) << sshift);
                }
            }
        } else {
            const int2* s2 = (const int2*)e32;
            for (int e = c0 + threadIdx.x * 2; e < c1; e += TPBW * 2) {
                int2 ss = s2[e >> 1];
                int2 dd = s2[(E + e) >> 1];
                int b0 = dd.x >> LBITS;
                int pos0 = atomicAdd(&sh[b0], 1);
                P[pos0] = (unsigned)ss.x | ((unsigned)(dd.x & (SBSZ - 1)) << sshift);
                if (e + 1 < c1) {
                    int b1i = dd.y >> LBITS;
                    int pos1 = atomicAdd(&sh[b1i], 1);
                    P[pos1] = (unsigned)ss.y | ((unsigned)(dd.y & (SBSZ - 1)) << sshift);
                }
            }
        }
    } else {
        for (int e = c0 + threadIdx.x; e < c1; e += TPBW) {
            long ee = (long)e << f;
            int s = e32[ee];
            int d = e32[(((long)E) << f) + ee];
            int b = d >> LBITS;
            int pos = atomicAdd(&sh[b], 1);
            P[pos] = (unsigned)s | ((unsigned)(d & (SBSZ - 1)) << sshift);
        }
    }
}

// per (bucket, quarter): LDS degree histogram -> plain partial store
__global__ void k_degS(const unsigned int* __restrict__ P, const int* __restrict__ base,
                       int n, int* __restrict__ cntP) {
    __shared__ int cnt[SBSZ];
    int bb = blockIdx.x >> 2, pp = blockIdx.x & (SPLIT - 1);
    int t = threadIdx.x;
    cnt[t] = 0;
    __syncthreads();
    int p0 = base[bb], len = base[bb + 1] - p0;
    int s0 = p0 + (int)((long)len * pp / SPLIT);
    int s1 = p0 + (int)((long)len * (pp + 1) / SPLIT);
    int sshift = 32 - LBITS;
    for (int p = s0 + t; p < s1; p += TPB)
        atomicAdd(&cnt[P[p] >> sshift], 1);
    __syncthreads();
    int v = (bb << LBITS) + t;
    if (v < n) cntP[pp * n + v] = cnt[t];
}

// node-parallel: cnt = sum partials -> dinv, g
__global__ void k_prep1(const int* __restrict__ cntP, const float* __restrict__ feat,
                        int n, float* __restrict__ dinv, float* __restrict__ g) {
    int v = blockIdx.x * TPB + threadIdx.x;
    if (v >= n) return;
    int c = 0;
#pragma unroll
    for (int pp = 0; pp < SPLIT; ++pp) c += cntP[pp * n + v];
    float di = rsqrtf((float)(c + 1));
    dinv[v] = di;
    g[v] = di * feat[v];
}

// per (bucket, quarter): partial A sums (LDS f32 atomics, 1/edge)
__global__ void k_aggAS(const unsigned int* __restrict__ P, const int* __restrict__ base,
                        int n, const float* __restrict__ g, float* __restrict__ AP) {
    __shared__ float A[SBSZ];
    int bb = blockIdx.x >> 2, pp = blockIdx.x & (SPLIT - 1);
    int t = threadIdx.x;
    A[t] = 0.f;
    __syncthreads();
    int p0 = base[bb], len = base[bb + 1] - p0;
    int s0 = p0 + (int)((long)len * pp / SPLIT);
    int s1 = p0 + (int)((long)len * (pp + 1) / SPLIT);
    int sshift = 32 - LBITS;
    unsigned smask = (1u << sshift) - 1;
    for (int p = s0 + t; p < s1; p += TPB) {
        unsigned e = P[p];
        atomicAdd(&A[e >> sshift], g[e & smask]);
    }
    __syncthreads();
    int v = (bb << LBITS) + t;
    if (v < n) AP[pp * n + v] = A[t];
}

// node-parallel: A = g_v + sum partials -> px -> signed qs = dinv*px; pd (fallback)
__global__ void k_prep2(const float* __restrict__ AP, const float* __restrict__ g,
                        const float* __restrict__ dinv, int n, const int* __restrict__ bzero,
                        float* __restrict__ qs, float2* __restrict__ pd,
                        float* __restrict__ Yagg) {
    int v = blockIdx.x * TPB + threadIdx.x;
    if (v >= n) return;
    float A = g[v];
#pragma unroll
    for (int pp = 0; pp < SPLIT; ++pp) A += AP[pp * n + v];
    float di = dinv[v];
    float px = di * A;
    qs[v] = di * px;
    if (!*bzero) {
        pd[v] = make_float2(px, di);
        float4* Y = (float4*)(Yagg + (size_t)v * 32);
#pragma unroll
        for (int i = 0; i < 8; ++i) Y[i] = make_float4(0.f, 0.f, 0.f, 0.f);
    }
}

// per (bucket, quarter): S± partials. ONE LDS atomic per edge (sign trick):
// only one of relu(±qs) is nonzero -> predicated address, |qs| value.
__global__ void k_aggTS(const unsigned int* __restrict__ P, const int* __restrict__ base,
                        int n, const float* __restrict__ qs, float2* __restrict__ SP2) {
    __shared__ float Sp[SBSZ], Sm[SBSZ];
    int bb = blockIdx.x >> 2, pp = blockIdx.x & (SPLIT - 1);
    int t = threadIdx.x;
    Sp[t] = 0.f; Sm[t] = 0.f;
    __syncthreads();
    int p0 = base[bb], len = base[bb + 1] - p0;
    int s0 = p0 + (int)((long)len * pp / SPLIT);
    int s1 = p0 + (int)((long)len * (pp + 1) / SPLIT);
    int sshift = 32 - LBITS;
    unsigned smask = (1u << sshift) - 1;
    for (int p = s0 + t; p < s1; p += TPB) {
        unsigned e = P[p];
        float q = qs[e & smask];
        int l = e >> sshift;
        float* addr = (q >= 0.f) ? &Sp[l] : &Sm[l];
        atomicAdd(addr, fabsf(q));
    }
    __syncthreads();
    int v = (bb << LBITS) + t;
    if (v < n) SP2[pp * n + v] = make_float2(Sp[t], Sm[t]);
}

// epilogue (fast, b1==0): thread per (v,k); S± = relu(±qs_v) + sum partials;
// out[v,k] = relu(dinv (S+ u+[k] + S- u-[k]) + b2[k]). Pure coalesced write.
__global__ void k_out(const float* __restrict__ qs, const float* __restrict__ dinv,
                      const float2* __restrict__ SP2, const float* __restrict__ upm,
                      const float* __restrict__ b2, const int* __restrict__ bzero,
                      int n, float* __restrict__ out) {
    if (!*bzero) return;
    __shared__ float su[192];    // u+ | u- | b2
    if (threadIdx.x < 192) su[threadIdx.x] = (threadIdx.x < 128) ? upm[threadIdx.x] : b2[threadIdx.x - 128];
    __syncthreads();
    int o = blockIdx.x * TPB + threadIdx.x;
    if (o >= n * 64) return;
    int v = o >> 6, k = o & 63;
    float qv = qs[v];
    float Sp = fmaxf(qv, 0.f), Sm = fmaxf(-qv, 0.f);
#pragma unroll
    for (int pp = 0; pp < SPLIT; ++pp) { float2 s = SP2[pp * n + v]; Sp += s.x; Sm += s.y; }
    float r = fmaf(dinv[v], fmaf(Sp, su[k], Sm * su[64 + k]), su[128 + k]);
    out[o] = fmaxf(r, 0.f);
}

// ---- general-b1 fallback (flag-gated; never taken in this bench) ----
__global__ void k_aggY(const int* __restrict__ e32, const int* __restrict__ flag,
                       int E, const int* __restrict__ bzero,
                       const float2* __restrict__ pd,
                       const float* __restrict__ W1, const float* __restrict__ b1,
                       float* __restrict__ Yagg) {
    if (*bzero) return;
    __shared__ float sw[32], sb[32];
    if (threadIdx.x < 32) { sw[threadIdx.x] = W1[threadIdx.x]; sb[threadIdx.x] = b1[threadIdx.x]; }
    __syncthreads();
    int sh = *flag;
    long stride = (long)gridDim.x * TPB;
    for (long e = (long)blockIdx.x * TPB + threadIdx.x; e < E; e += stride) {
        int s = e32[e << sh];
        int d = e32[((long)E + e) << sh];
        float2 p = pd[s];
#pragma unroll
        for (int c = 0; c < 32; ++c) {
            float y = p.y * fmaxf(fmaf(sw[c], p.x, sb[c] * p.y), 0.f);
            atomicAdd(&Yagg[(size_t)d * 32 + c], y);
        }
    }
}

__global__ void k_final_gen(const float2* __restrict__ pd, const float* __restrict__ Yagg,
                            const float* __restrict__ W1, const float* __restrict__ b1,
                            const float* __restrict__ W2, const float* __restrict__ b2,
                            const int* __restrict__ bzero, int n, float* __restrict__ out) {
    if (*bzero) return;
    __shared__ float sW[32 * 64];
    __shared__ float sb2[64];
    __shared__ float sagg[8][33];
    int t = threadIdx.x;
    for (int i = t; i < 32 * 64; i += TPB) sW[i] = W2[i];
    if (t < 64) sb2[t] = b2[t];
    int vl = t >> 5, c = t & 31;
    int nblk = (n + 7) / 8;
    for (int blk = blockIdx.x; blk < nblk; blk += gridDim.x) {
        int v = blk * 8 + vl;
        float a = 0.f;
        if (v < n) {
            float2 p = pd[v];
            float dv = p.y;
            float yv = fmaxf(fmaf(W1[c], p.x, b1[c] * p.y), 0.f);
            a = dv * (dv * yv + Yagg[(size_t)v * 32 + c]);
        }
        __syncthreads();
        sagg[vl][c] = a;
        __syncthreads();
        if (v < n) {
            float o0 = sb2[c], o1 = sb2[c + 32];
#pragma unroll
            for (int j = 0; j < 32; ++j) {
                float x = sagg[vl][j];
                o0 += x * sW[j * 64 + c];
                o1 += x * sW[j * 64 + 32 + c];
            }
            out[(size_t)v * 64 + c]      = fmaxf(o0, 0.f);
            out[(size_t)v * 64 + 32 + c] = fmaxf(o1, 0.f);
        }
    }
}

static inline size_t align256(size_t x) { return (x + 255) & ~(size_t)255; }

extern "C" void kernel_launch(void* const* d_in, const int* in_sizes, int n_in,
                              void* d_out, int out_size, void* d_ws, size_t ws_size,
                              hipStream_t stream) {
    const float* feat = (const float*)d_in[0];
    const int*   e32  = (const int*)d_in[1];
    const float* W1   = (const float*)d_in[2];
    const float* b1   = (const float*)d_in[3];
    const float* W2   = (const float*)d_in[4];
    const float* b2   = (const float*)d_in[5];
    float* out = (float*)d_out;

    int n = in_sizes[0];         // 100000
    int E = in_sizes[1] / 2;     // 3200000

    int NSB = (n + SBSZ - 1) >> LBITS;                    // 391 @ n=100K

    char* w = (char*)d_ws;
    size_t off = 0;
    auto alloc = [&](size_t bytes) -> char* { char* p = w + off; off = align256(off + bytes); return p; };
    unsigned int* P = (unsigned int*)alloc((size_t)E * 4);
    int*    H     = (int*)alloc((size_t)NCHUNK * NSB * 4);
    int*    P2    = (int*)alloc((size_t)NCHUNK * NSB * 4);
    int*    colsum= (int*)alloc((size_t)NSB * 4);
    int*    base  = (int*)alloc((size_t)(NSB + 1) * 4);
    int*    cntP  = (int*)alloc((size_t)SPLIT * n * 4);
    float*  AP    = (float*)alloc((size_t)SPLIT * n * 4);
    float2* SP2   = (float2*)alloc((size_t)SPLIT * n * 8);
    float*  dinv  = (float*)alloc((size_t)n * 4);
    float*  g     = (float*)alloc((size_t)n * 4);
    float*  qs    = (float*)alloc((size_t)n * 4);
    float2* pd    = (float2*)alloc((size_t)n * 8);
    float*  upm   = (float*)alloc(128 * 4);
    int*    flag  = (int*)alloc(4);
    int*    bzero = (int*)alloc(4);
    float*  Yagg  = (float*)alloc((size_t)n * 32 * 4);    // general path only

    int chunk = (E + NCHUNK - 1) / NCHUNK;
    if (chunk & 1) chunk++;                  // even chunk => aligned paired loads
    int gN = (n + TPB - 1) / TPB;
    int gS = NSB * SPLIT;
    int gO = (n * 64 + TPB - 1) / TPB;

    hipLaunchKernelGGL(k_init,      dim3(1),      dim3(TPB),  0, stream, e32, E, flag, W1, b1, W2, upm, bzero);
    hipLaunchKernelGGL(k_hist2,     dim3(NCHUNK), dim3(TPBW), 0, stream, e32, flag, E, NSB, chunk, H);
    hipLaunchKernelGGL(k_colscan,   dim3(NSB),    dim3(NCHUNK), 0, stream, H, NSB, P2, colsum);
    hipLaunchKernelGGL(k_scan,      dim3(1),      dim3(TPB),  0, stream, colsum, NSB, E, base);
    hipLaunchKernelGGL(k_part2,     dim3(NCHUNK), dim3(TPBW), 0, stream, e32, flag, E, NSB, base, P2, P, chunk);
    hipLaunchKernelGGL(k_degS,      dim3(gS),     dim3(TPB),  0, stream, P, base, n, cntP);
    hipLaunchKernelGGL(k_prep1,     dim3(gN),     dim3(TPB),  0, stream, cntP, feat, n, dinv, g);
    hipLaunchKernelGGL(k_aggAS,     dim3(gS),     dim3(TPB),  0, stream, P, base, n, g, AP);
    hipLaunchKernelGGL(k_prep2,     dim3(gN),     dim3(TPB),  0, stream, AP, g, dinv, n, bzero, qs, pd, Yagg);
    hipLaunchKernelGGL(k_aggTS,     dim3(gS),     dim3(TPB),  0, stream, P, base, n, qs, SP2);
    hipLaunchKernelGGL(k_out,       dim3(gO),     dim3(TPB),  0, stream, qs, dinv, SP2, upm, b2, bzero, n, out);
    hipLaunchKernelGGL(k_aggY,      dim3(512),    dim3(TPB),  0, stream, e32, flag, E, bzero, pd, W1, b1, Yagg);
    hipLaunchKernelGGL(k_final_gen, dim3(1024),   dim3(TPB),  0, stream, pd, Yagg, W1, b1, W2, b2, bzero, n, out);
}

// Round 12
// 107.327 us; speedup vs baseline: 4.0948x; 1.1255x over previous
//
#include <hip/hip_runtime.h>

// ---------------------------------------------------------------------------
// 2-layer GCN, symmetric norm + self loops — rank-2 scalarized, LDS-atomic
// segment sums over a dst-bucket partition, SPLIT sub-blocks per bucket.
//
// feat is [n,1] and b1 == 0 (device-checked)  =>
//   px_v = dinv_v * (g_v + sum g_src),  g = dinv*feat
//   qs_v = dinv_v * px_v   (signed; q± = relu(±qs), only one nonzero)
//   out[v,k] = relu( dinv_v (S+_v u+[k] + S-_v u-[k]) + b2[k] ),
//   S±_v = relu(±qs_v) + sum relu(±qs_src),  u± = max(±W1,0) @ W2 (2x64)
//
// R4: global f32 atomics ~32B HBM writeback each -> never per-edge.
// R5: partition scatter needs long per-bucket runs: LBITS=9 -> ~64-edge
//     (256B) runs per (chunk,bucket).
// R6: agg kernels need ~24 waves/CU to hide gather latency.
// R7: per-CU LDS atomic pipe saturates -> 1 atomic/edge max everywhere.
// R8/R9: deterministic 2D-histogram partition (no reservation atomics).
// R10: __threadfence() = L2 writeback on gfx950 (~100µs over 1.5K blocks);
//      kernel launches ARE the global barrier. No cross-block fusion.
// ---------------------------------------------------------------------------

#define TPB 256
#define TPBW 1024     // wide blocks: hist + partition
#define ATPB 512      // agg kernel block size (1:1 with SBSZ)
#define NSBMAX 1024   // max buckets (LDS arrays)
#define SBSZ 512      // nodes per bucket (= 1 << LBITS)
#define LBITS 9
#define SPLIT 4       // sub-blocks per bucket in agg kernels
#define NCHUNK 256    // edge chunks (= partition/hist grid)

// Fused init: edge-layout detect (int64 low/high pairs vs int32; ids < 2^31
// so int64 high words are 0 — sample odd 32-bit positions) + u± = max(±W1,0)@W2
// + bzero = all(b1==0). One block.
__global__ void k_init(const int* __restrict__ e32, int E, int* __restrict__ flag,
                       const float* __restrict__ W1, const float* __restrict__ b1,
                       const float* __restrict__ W2, float* __restrict__ upm,
                       int* __restrict__ bzero) {
    __shared__ int ok;
    __shared__ float sw[32], sb[32];
    int t = threadIdx.x;
    if (t == 0) ok = 1;
    if (t < 32) { sw[t] = W1[t]; sb[t] = b1[t]; }
    __syncthreads();
    int stride = E / 2048; if (stride < 1) stride = 1;
    bool bad = false;
#pragma unroll
    for (int i = 0; i < 8; ++i) {
        long k = (long)(t * 8 + i) * stride + 1;
        if (k < E && e32[2 * k + 1] != 0) bad = true;
    }
    if (bad) atomicAnd(&ok, 0);
    if (t < 64) {
        float up = 0.f, um = 0.f;
#pragma unroll
        for (int c = 0; c < 32; ++c) {
            float w = sw[c];
            float w2 = W2[c * 64 + t];
            up = fmaf(fmaxf(w, 0.f), w2, up);
            um = fmaf(fmaxf(-w, 0.f), w2, um);
        }
        upm[t] = up;
        upm[64 + t] = um;
    }
    __syncthreads();
    if (t == 0) {
        *flag = ok;   // 1 => int64 (shift 1), 0 => int32
        int z = 1;
        for (int c = 0; c < 32; ++c) if (sb[c] != 0.f) z = 0;
        *bzero = z;
    }
}

// per-chunk bucket histogram; stores the FULL row H[c][b]. Paired-edge loads
// (chunk even, E even => aligned int4/int2 pairs).
__global__ void k_hist2(const int* __restrict__ e32, const int* __restrict__ flag,
                        int E, int NSB, int chunk, int* __restrict__ H) {
    __shared__ int sh[NSBMAX];
    int c = blockIdx.x;
    int c0 = c * chunk;
    int c1 = c0 + chunk; if (c1 > E) c1 = E;
    for (int i = threadIdx.x; i < NSB; i += TPBW) sh[i] = 0;
    __syncthreads();
    int f = *flag;
    if (((E | c0) & 1) == 0) {
        if (f) {
            const int4* d4 = (const int4*)e32;
            for (int e = c0 + threadIdx.x * 2; e < c1; e += TPBW * 2) {
                int4 dd = d4[(E + e) >> 1];          // dsts of e, e+1 at .x, .z
                atomicAdd(&sh[dd.x >> LBITS], 1);
                if (e + 1 < c1) atomicAdd(&sh[dd.z >> LBITS], 1);
            }
        } else {
            const int2* d2 = (const int2*)e32;
            for (int e = c0 + threadIdx.x * 2; e < c1; e += TPBW * 2) {
                int2 dd = d2[(E + e) >> 1];
                atomicAdd(&sh[dd.x >> LBITS], 1);
                if (e + 1 < c1) atomicAdd(&sh[dd.y >> LBITS], 1);
            }
        }
    } else {
        for (int e = c0 + threadIdx.x; e < c1; e += TPBW) {
            int d = e32[((long)E + e) << f];
            atomicAdd(&sh[d >> LBITS], 1);
        }
    }
    __syncthreads();
    for (int i = threadIdx.x; i < NSB; i += TPBW) H[(size_t)c * NSB + i] = sh[i];
}

// per bucket: exclusive scan of H column over chunks -> P2; total -> colsum
__global__ void k_colscan(const int* __restrict__ H, int NSB,
                          int* __restrict__ P2, int* __restrict__ colsum) {
    __shared__ int s[NCHUNK];
    int b = blockIdx.x, t = threadIdx.x;
    int v = H[(size_t)t * NSB + b];
    s[t] = v;
    __syncthreads();
    for (int off = 1; off < NCHUNK; off <<= 1) {
        int x = s[t];
        int u = (t >= off) ? s[t - off] : 0;
        __syncthreads();
        s[t] = x + u;
        __syncthreads();
    }
    P2[(size_t)t * NSB + b] = s[t] - v;
    if (t == NCHUNK - 1) colsum[b] = s[t];
}

// one-block exclusive scan of NSB bucket totals -> base
__global__ void k_scan(const int* __restrict__ colsum, int NSB, int E,
                       int* __restrict__ base) {
    __shared__ int s[TPB];
    int K = (NSB + TPB - 1) / TPB;
    int t = threadIdx.x;
    int i0 = t * K;
    int tot = 0;
    for (int k = 0; k < K; ++k) { int i = i0 + k; if (i < NSB) tot += colsum[i]; }
    s[t] = tot;
    __syncthreads();
    for (int off = 1; off < TPB; off <<= 1) {
        int v = s[t];
        int u = (t >= off) ? s[t - off] : 0;
        __syncthreads();
        s[t] = v + u;
        __syncthreads();
    }
    int run = s[t] - tot;   // exclusive
    for (int k = 0; k < K; ++k) {
        int i = i0 + k;
        if (i < NSB) { base[i] = run; run += colsum[i]; }
    }
    if (t == 0) base[NSB] = E;
}

// partition bucket-major with deterministic offsets (base[b]+P2[c][b]);
// ONE LDS atomic per edge; paired-edge loads; packed (ldst<<23)|src.
__global__ void k_part2(const int* __restrict__ e32, const int* __restrict__ flag,
                        int E, int NSB, const int* __restrict__ base,
                        const int* __restrict__ P2, unsigned int* __restrict__ P,
                        int chunk) {
    __shared__ int sh[NSBMAX];
    int c = blockIdx.x;
    int c0 = c * chunk;
    int c1 = c0 + chunk; if (c1 > E) c1 = E;
    for (int i = threadIdx.x; i < NSB; i += TPBW)
        sh[i] = base[i] + P2[(size_t)c * NSB + i];
    __syncthreads();
    int f = *flag;
    int sshift = 32 - LBITS;
    if (((E | c0) & 1) == 0) {
        if (f) {
            const int4* s4 = (const int4*)e32;
            for (int e = c0 + threadIdx.x * 2; e < c1; e += TPBW * 2) {
                int4 ss = s4[e >> 1];                // srcs of e, e+1 at .x, .z
                int4 dd = s4[(E + e) >> 1];          // dsts of e, e+1 at .x, .z
                int b0 = dd.x >> LBITS;
                int pos0 = atomicAdd(&sh[b0], 1);
                P[pos0] = (unsigned)ss.x | ((unsigned)(dd.x & (SBSZ - 1)) << sshift);
                if (e + 1 < c1) {
                    int b1i = dd.z >> LBITS;
                    int pos1 = atomicAdd(&sh[b1i], 1);
                    P[pos1] = (unsigned)ss.z | ((unsigned)(dd.z & (SBSZ - 1)) << sshift);
                }
            }
        } else {
            const int2* s2 = (const int2*)e32;
            for (int e = c0 + threadIdx.x * 2; e < c1; e += TPBW * 2) {
                int2 ss = s2[e >> 1];
                int2 dd = s2[(E + e) >> 1];
                int b0 = dd.x >> LBITS;
                int pos0 = atomicAdd(&sh[b0], 1);
                P[pos0] = (unsigned)ss.x | ((unsigned)(dd.x & (SBSZ - 1)) << sshift);
                if (e + 1 < c1) {
                    int b1i = dd.y >> LBITS;
                    int pos1 = atomicAdd(&sh[b1i], 1);
                    P[pos1] = (unsigned)ss.y | ((unsigned)(dd.y & (SBSZ - 1)) << sshift);
                }
            }
        }
    } else {
        for (int e = c0 + threadIdx.x; e < c1; e += TPBW) {
            long ee = (long)e << f;
            int s = e32[ee];
            int d = e32[(((long)E) << f) + ee];
            int b = d >> LBITS;
            int pos = atomicAdd(&sh[b], 1);
            P[pos] = (unsigned)s | ((unsigned)(d & (SBSZ - 1)) << sshift);
        }
    }
}

// per (bucket, quarter): LDS degree histogram -> plain partial store
__global__ void k_degS(const unsigned int* __restrict__ P, const int* __restrict__ base,
                       int n, int* __restrict__ cntP) {
    __shared__ int cnt[SBSZ];
    int bb = blockIdx.x >> 2, pp = blockIdx.x & (SPLIT - 1);
    int t = threadIdx.x;
    cnt[t] = 0;
    __syncthreads();
    int p0 = base[bb], len = base[bb + 1] - p0;
    int s0 = p0 + (int)((long)len * pp / SPLIT);
    int s1 = p0 + (int)((long)len * (pp + 1) / SPLIT);
    int sshift = 32 - LBITS;
    for (int p = s0 + t; p < s1; p += ATPB)
        atomicAdd(&cnt[P[p] >> sshift], 1);
    __syncthreads();
    int v = (bb << LBITS) + t;
    if (v < n) cntP[pp * n + v] = cnt[t];
}

// node-parallel: cnt = sum partials -> dinv, g
__global__ void k_prep1(const int* __restrict__ cntP, const float* __restrict__ feat,
                        int n, float* __restrict__ dinv, float* __restrict__ g) {
    int v = blockIdx.x * TPB + threadIdx.x;
    if (v >= n) return;
    int c = 0;
#pragma unroll
    for (int pp = 0; pp < SPLIT; ++pp) c += cntP[pp * n + v];
    float di = rsqrtf((float)(c + 1));
    dinv[v] = di;
    g[v] = di * feat[v];
}

// per (bucket, quarter): partial A sums (LDS f32 atomics, 1/edge)
__global__ void k_aggAS(const unsigned int* __restrict__ P, const int* __restrict__ base,
                        int n, const float* __restrict__ g, float* __restrict__ AP) {
    __shared__ float A[SBSZ];
    int bb = blockIdx.x >> 2, pp = blockIdx.x & (SPLIT - 1);
    int t = threadIdx.x;
    A[t] = 0.f;
    __syncthreads();
    int p0 = base[bb], len = base[bb + 1] - p0;
    int s0 = p0 + (int)((long)len * pp / SPLIT);
    int s1 = p0 + (int)((long)len * (pp + 1) / SPLIT);
    int sshift = 32 - LBITS;
    unsigned smask = (1u << sshift) - 1;
    for (int p = s0 + t; p < s1; p += ATPB) {
        unsigned e = P[p];
        atomicAdd(&A[e >> sshift], g[e & smask]);
    }
    __syncthreads();
    int v = (bb << LBITS) + t;
    if (v < n) AP[pp * n + v] = A[t];
}

// node-parallel: A = g_v + sum partials -> px -> signed qs = dinv*px; pd (fallback)
__global__ void k_prep2(const float* __restrict__ AP, const float* __restrict__ g,
                        const float* __restrict__ dinv, int n, const int* __restrict__ bzero,
                        float* __restrict__ qs, float2* __restrict__ pd,
                        float* __restrict__ Yagg) {
    int v = blockIdx.x * TPB + threadIdx.x;
    if (v >= n) return;
    float A = g[v];
#pragma unroll
    for (int pp = 0; pp < SPLIT; ++pp) A += AP[pp * n + v];
    float di = dinv[v];
    float px = di * A;
    qs[v] = di * px;
    if (!*bzero) {
        pd[v] = make_float2(px, di);
        float4* Y = (float4*)(Yagg + (size_t)v * 32);
#pragma unroll
        for (int i = 0; i < 8; ++i) Y[i] = make_float4(0.f, 0.f, 0.f, 0.f);
    }
}

// per (bucket, quarter): S± partials. ONE LDS atomic per edge (sign trick):
// only one of relu(±qs) is nonzero -> predicated address, |qs| value.
__global__ void k_aggTS(const unsigned int* __restrict__ P, const int* __restrict__ base,
                        int n, const float* __restrict__ qs, float2* __restrict__ SP2) {
    __shared__ float Sp[SBSZ], Sm[SBSZ];
    int bb = blockIdx.x >> 2, pp = blockIdx.x & (SPLIT - 1);
    int t = threadIdx.x;
    Sp[t] = 0.f; Sm[t] = 0.f;
    __syncthreads();
    int p0 = base[bb], len = base[bb + 1] - p0;
    int s0 = p0 + (int)((long)len * pp / SPLIT);
    int s1 = p0 + (int)((long)len * (pp + 1) / SPLIT);
    int sshift = 32 - LBITS;
    unsigned smask = (1u << sshift) - 1;
    for (int p = s0 + t; p < s1; p += ATPB) {
        unsigned e = P[p];
        float q = qs[e & smask];
        int l = e >> sshift;
        float* addr = (q >= 0.f) ? &Sp[l] : &Sm[l];
        atomicAdd(addr, fabsf(q));
    }
    __syncthreads();
    int v = (bb << LBITS) + t;
    if (v < n) SP2[pp * n + v] = make_float2(Sp[t], Sm[t]);
}

// epilogue (fast, b1==0): thread per (v, 4 channels); float4 coalesced write.
__global__ void k_out(const float* __restrict__ qs, const float* __restrict__ dinv,
                      const float2* __restrict__ SP2, const float* __restrict__ upm,
                      const float* __restrict__ b2, const int* __restrict__ bzero,
                      int n, float* __restrict__ out) {
    if (!*bzero) return;
    __shared__ float su[192];    // u+ | u- | b2
    if (threadIdx.x < 192) su[threadIdx.x] = (threadIdx.x < 128) ? upm[threadIdx.x] : b2[threadIdx.x - 128];
    __syncthreads();
    int o = blockIdx.x * TPB + threadIdx.x;
    if (o >= n * 16) return;
    int v = o >> 4, kq = (o & 15) << 2;
    float qv = qs[v];
    float Sp = fmaxf(qv, 0.f), Sm = fmaxf(-qv, 0.f);
#pragma unroll
    for (int pp = 0; pp < SPLIT; ++pp) { float2 s = SP2[pp * n + v]; Sp += s.x; Sm += s.y; }
    float dv = dinv[v];
    Sp *= dv; Sm *= dv;
    float4 r;
    r.x = fmaxf(fmaf(Sp, su[kq],     fmaf(Sm, su[64 + kq],     su[128 + kq])),     0.f);
    r.y = fmaxf(fmaf(Sp, su[kq + 1], fmaf(Sm, su[64 + kq + 1], su[128 + kq + 1])), 0.f);
    r.z = fmaxf(fmaf(Sp, su[kq + 2], fmaf(Sm, su[64 + kq + 2], su[128 + kq + 2])), 0.f);
    r.w = fmaxf(fmaf(Sp, su[kq + 3], fmaf(Sm, su[64 + kq + 3], su[128 + kq + 3])), 0.f);
    *(float4*)(out + (size_t)v * 64 + kq) = r;
}

// ---- general-b1 fallback (flag-gated; never taken in this bench) ----
__global__ void k_aggY(const int* __restrict__ e32, const int* __restrict__ flag,
                       int E, const int* __restrict__ bzero,
                       const float2* __restrict__ pd,
                       const float* __restrict__ W1, const float* __restrict__ b1,
                       float* __restrict__ Yagg) {
    if (*bzero) return;
    __shared__ float sw[32], sb[32];
    if (threadIdx.x < 32) { sw[threadIdx.x] = W1[threadIdx.x]; sb[threadIdx.x] = b1[threadIdx.x]; }
    __syncthreads();
    int sh = *flag;
    long stride = (long)gridDim.x * TPB;
    for (long e = (long)blockIdx.x * TPB + threadIdx.x; e < E; e += stride) {
        int s = e32[e << sh];
        int d = e32[((long)E + e) << sh];
        float2 p = pd[s];
#pragma unroll
        for (int c = 0; c < 32; ++c) {
            float y = p.y * fmaxf(fmaf(sw[c], p.x, sb[c] * p.y), 0.f);
            atomicAdd(&Yagg[(size_t)d * 32 + c], y);
        }
    }
}

__global__ void k_final_gen(const float2* __restrict__ pd, const float* __restrict__ Yagg,
                            const float* __restrict__ W1, const float* __restrict__ b1,
                            const float* __restrict__ W2, const float* __restrict__ b2,
                            const int* __restrict__ bzero, int n, float* __restrict__ out) {
    if (*bzero) return;
    __shared__ float sW[32 * 64];
    __shared__ float sb2[64];
    __shared__ float sagg[8][33];
    int t = threadIdx.x;
    for (int i = t; i < 32 * 64; i += TPB) sW[i] = W2[i];
    if (t < 64) sb2[t] = b2[t];
    int vl = t >> 5, c = t & 31;
    int nblk = (n + 7) / 8;
    for (int blk = blockIdx.x; blk < nblk; blk += gridDim.x) {
        int v = blk * 8 + vl;
        float a = 0.f;
        if (v < n) {
            float2 p = pd[v];
            float dv = p.y;
            float yv = fmaxf(fmaf(W1[c], p.x, b1[c] * p.y), 0.f);
            a = dv * (dv * yv + Yagg[(size_t)v * 32 + c]);
        }
        __syncthreads();
        sagg[vl][c] = a;
        __syncthreads();
        if (v < n) {
            float o0 = sb2[c], o1 = sb2[c + 32];
#pragma unroll
            for (int j = 0; j < 32; ++j) {
                float x = sagg[vl][j];
                o0 += x * sW[j * 64 + c];
                o1 += x * sW[j * 64 + 32 + c];
            }
            out[(size_t)v * 64 + c]      = fmaxf(o0, 0.f);
            out[(size_t)v * 64 + 32 + c] = fmaxf(o1, 0.f);
        }
    }
}

static inline size_t align256(size_t x) { return (x + 255) & ~(size_t)255; }

extern "C" void kernel_launch(void* const* d_in, const int* in_sizes, int n_in,
                              void* d_out, int out_size, void* d_ws, size_t ws_size,
                              hipStream_t stream) {
    const float* feat = (const float*)d_in[0];
    const int*   e32  = (const int*)d_in[1];
    const float* W1   = (const float*)d_in[2];
    const float* b1   = (const float*)d_in[3];
    const float* W2   = (const float*)d_in[4];
    const float* b2   = (const float*)d_in[5];
    float* out = (float*)d_out;

    int n = in_sizes[0];         // 100000
    int E = in_sizes[1] / 2;     // 3200000

    int NSB = (n + SBSZ - 1) >> LBITS;                    // 196 @ n=100K

    char* w = (char*)d_ws;
    size_t off = 0;
    auto alloc = [&](size_t bytes) -> char* { char* p = w + off; off = align256(off + bytes); return p; };
    unsigned int* P = (unsigned int*)alloc((size_t)E * 4);
    int*    H     = (int*)alloc((size_t)NCHUNK * NSB * 4);
    int*    P2    = (int*)alloc((size_t)NCHUNK * NSB * 4);
    int*    colsum= (int*)alloc((size_t)NSB * 4);
    int*    base  = (int*)alloc((size_t)(NSB + 1) * 4);
    int*    cntP  = (int*)alloc((size_t)SPLIT * n * 4);
    float*  AP    = (float*)alloc((size_t)SPLIT * n * 4);
    float2* SP2   = (float2*)alloc((size_t)SPLIT * n * 8);
    float*  dinv  = (float*)alloc((size_t)n * 4);
    float*  g     = (float*)alloc((size_t)n * 4);
    float*  qs    = (float*)alloc((size_t)n * 4);
    float2* pd    = (float2*)alloc((size_t)n * 8);
    float*  upm   = (float*)alloc(128 * 4);
    int*    flag  = (int*)alloc(4);
    int*    bzero = (int*)alloc(4);
    float*  Yagg  = (float*)alloc((size_t)n * 32 * 4);    // general path only

    int chunk = (E + NCHUNK - 1) / NCHUNK;
    if (chunk & 1) chunk++;                  // even chunk => aligned paired loads
    int gN = (n + TPB - 1) / TPB;
    int gS = NSB * SPLIT;                    // 784 blocks of ATPB=512
    int gO = (n * 16 + TPB - 1) / TPB;       // float4 epilogue

    hipLaunchKernelGGL(k_init,      dim3(1),      dim3(TPB),  0, stream, e32, E, flag, W1, b1, W2, upm, bzero);
    hipLaunchKernelGGL(k_hist2,     dim3(NCHUNK), dim3(TPBW), 0, stream, e32, flag, E, NSB, chunk, H);
    hipLaunchKernelGGL(k_colscan,   dim3(NSB),    dim3(NCHUNK), 0, stream, H, NSB, P2, colsum);
    hipLaunchKernelGGL(k_scan,      dim3(1),      dim3(TPB),  0, stream, colsum, NSB, E, base);
    hipLaunchKernelGGL(k_part2,     dim3(NCHUNK), dim3(TPBW), 0, stream, e32, flag, E, NSB, base, P2, P, chunk);
    hipLaunchKernelGGL(k_degS,      dim3(gS),     dim3(ATPB), 0, stream, P, base, n, cntP);
    hipLaunchKernelGGL(k_prep1,     dim3(gN),     dim3(TPB),  0, stream, cntP, feat, n, dinv, g);
    hipLaunchKernelGGL(k_aggAS,     dim3(gS),     dim3(ATPB), 0, stream, P, base, n, g, AP);
    hipLaunchKernelGGL(k_prep2,     dim3(gN),     dim3(TPB),  0, stream, AP, g, dinv, n, bzero, qs, pd, Yagg);
    hipLaunchKernelGGL(k_aggTS,     dim3(gS),     dim3(ATPB), 0, stream, P, base, n, qs, SP2);
    hipLaunchKernelGGL(k_out,       dim3(gO),     dim3(TPB),  0, stream, qs, dinv, SP2, upm, b2, bzero, n, out);
    hipLaunchKernelGGL(k_aggY,      dim3(256),    dim3(TPB),  0, stream, e32, flag, E, bzero, pd, W1, b1, Yagg);
    hipLaunchKernelGGL(k_final_gen, dim3(256),    dim3(TPB),  0, stream, pd, Yagg, W1, b1, W2, b2, bzero, n, out);
}